// Round 2
// baseline (595.850 us; speedup 1.0000x reference)
//
#include <hip/hip_runtime.h>

// Soft-circuit FP32 scale-by-2^k, reduced to integer bit ops.
// Row layout (element e <-> bit e of packed word):
//   bit 0      = sign
//   bits 1..8  = exponent, element 1 = MSB
//   bits 9..31 = mantissa, element 9 = MSB
//
// v2 structure: one row per 4-lane QUAD (was 8-lane group).
//  - each lane loads float4 at row*8+g and row*8+4+g  -> 32 B of the row
//  - OR-reduce across the quad via DPP quad_perm (VALU only, no LDS pipe)
//  - each thread processes TWO far-apart rows for 2x memory-level parallelism
// Memory-bound: 804 MB logical traffic -> ~128 us floor @6.3 TB/s.

// native vector type for __builtin_nontemporal_store (HIP_vector_type is rejected)
typedef float fvec4 __attribute__((ext_vector_type(4)));

__device__ __forceinline__ unsigned rev8(unsigned v) {
    // reverse the low 8 bits
    return __builtin_bitreverse32(v) >> 24;
}

__device__ __forceinline__ unsigned nib4(const float4 v) {
    return (unsigned)(v.x != 0.0f)
         | ((unsigned)(v.y != 0.0f) << 1)
         | ((unsigned)(v.z != 0.0f) << 2)
         | ((unsigned)(v.w != 0.0f) << 3);
}

// OR-reduce across the 4 lanes of a quad using DPP quad_perm.
// VALU pipe only -- replaces the ds_bpermute chain __shfl_xor would emit.
__device__ __forceinline__ unsigned quad_or(unsigned w) {
    // quad_perm [1,0,3,2] = 0xB1  (lane ^ 1)
    w |= (unsigned)__builtin_amdgcn_update_dpp(0, (int)w, 0xB1, 0xF, 0xF, true);
    // quad_perm [2,3,0,1] = 0x4E  (lane ^ 2)
    w |= (unsigned)__builtin_amdgcn_update_dpp(0, (int)w, 0x4E, 0xF, 0xF, true);
    return w;
}

// identical arithmetic to the harness-verified v1 kernel
__device__ __forceinline__ unsigned scale_word(unsigned xw, unsigned kw) {
    unsigned ek   = rev8((kw >> 1) & 0xFFu);                                   // exponent of k
    unsigned val  = 0x80u | (__builtin_bitreverse32((kw >> 9) & 0x7Fu) >> 25); // 1.m (8-bit)
    unsigned s    = (ek - 127u) & 7u;
    unsigned kabs = val >> (7u - s);
    unsigned kfin = (kw & 1u) ? ((0u - kabs) & 0xFFu) : kabs;
    unsigned ex   = rev8((xw >> 1) & 0xFFu);
    unsigned enew = (ex + kfin) & 0xFFu;
    unsigned scaled = (xw & 1u) | (rev8(enew) << 1) | (xw & 0xFFFFFE00u);
    return ((kw & ~1u) == 0u) ? xw : scaled;
}

__device__ __forceinline__ fvec4 unpack4(unsigned res, unsigned sh) {
    fvec4 o;
    o.x = (float)((res >> (sh + 0u)) & 1u);
    o.y = (float)((res >> (sh + 1u)) & 1u);
    o.z = (float)((res >> (sh + 2u)) & 1u);
    o.w = (float)((res >> (sh + 3u)) & 1u);
    return o;
}

__global__ __launch_bounds__(256) void spike_scale_kernel(
        const float4* __restrict__ x4,
        const float4* __restrict__ k4,
        float4* __restrict__ o4,
        int nrows, int half) {
    int t  = blockIdx.x * 256 + threadIdx.x;
    int q0 = t >> 2;                 // first row this quad handles
    if (q0 >= half) return;
    unsigned g  = (unsigned)(t & 3); // lane within quad
    unsigned sh = g * 4u;

    int  q1   = q0 + half;           // second (far-apart) row
    bool has1 = (q1 < nrows);
    int  q1c  = has1 ? q1 : q0;      // clamp so loads stay unconditional

    int i00 = q0 * 8 + (int)g;       // float4 index: low half of row q0
    int i01 = i00 + 4;               // high half of row q0
    int i10 = q1c * 8 + (int)g;
    int i11 = i10 + 4;

    // issue all 8 global loads up front (independent -> max MLP)
    float4 x00 = x4[i00];
    float4 x01 = x4[i01];
    float4 k00 = k4[i00];
    float4 k01 = k4[i01];
    float4 x10 = x4[i10];
    float4 x11 = x4[i11];
    float4 k10 = k4[i10];
    float4 k11 = k4[i11];

    unsigned xw0 = quad_or((nib4(x00) << sh) | (nib4(x01) << (16u + sh)));
    unsigned kw0 = quad_or((nib4(k00) << sh) | (nib4(k01) << (16u + sh)));
    unsigned xw1 = quad_or((nib4(x10) << sh) | (nib4(x11) << (16u + sh)));
    unsigned kw1 = quad_or((nib4(k10) << sh) | (nib4(k11) << (16u + sh)));

    unsigned r0 = scale_word(xw0, kw0);
    unsigned r1 = scale_word(xw1, kw1);

    // output is never re-read by this kernel: nontemporal to spare L3 for inputs
    fvec4* ov = (fvec4*)o4;
    __builtin_nontemporal_store(unpack4(r0, sh),       &ov[i00]);
    __builtin_nontemporal_store(unpack4(r0, 16u + sh), &ov[i01]);
    if (has1) {
        __builtin_nontemporal_store(unpack4(r1, sh),       &ov[i10]);
        __builtin_nontemporal_store(unpack4(r1, 16u + sh), &ov[i11]);
    }
}

extern "C" void kernel_launch(void* const* d_in, const int* in_sizes, int n_in,
                              void* d_out, int out_size, void* d_ws, size_t ws_size,
                              hipStream_t stream) {
    const float4* x4 = (const float4*)d_in[0];
    const float4* k4 = (const float4*)d_in[1];
    float4* o4 = (float4*)d_out;

    int n_elems  = in_sizes[0];         // N * 32 floats
    int nrows    = n_elems / 32;
    int half     = (nrows + 1) / 2;     // rows per "pass"; each thread does 2
    int nthreads = half * 4;            // 4 lanes per row
    int blocks   = (nthreads + 255) / 256;

    spike_scale_kernel<<<blocks, 256, 0, stream>>>(x4, k4, o4, nrows, half);
}

// Round 3
// 565.044 us; speedup vs baseline: 1.0545x; 1.0545x over previous
//
#include <hip/hip_runtime.h>

// Soft-circuit FP32 scale-by-2^k, reduced to integer bit ops.
// Row layout (element e <-> bit e of packed word):
//   bit 0      = sign
//   bits 1..8  = exponent, element 1 = MSB
//   bits 9..31 = mantissa, element 9 = MSB
//
// v3: v1's layout (8 lanes/row, fully coalesced 1KB-per-instruction VMEM,
// plain stores) with the cross-lane traffic minimized:
//  - lanes g>=3 pass their x nibble through untouched (mantissa), so the
//    full-row 64-bit shfl-OR chain (6 serial DS ops) is unnecessary;
//  - scale arithmetic needs only bits 0..15 of x and k -> low-quad DPP
//    quad_perm OR (2 VALU ops, LDS pipe untouched);
//  - k==0 test is a 1-bit OR over the 8-lane group -> one __ballot + byte
//    extract.
// Memory-bound: 768 MB logical traffic.

__device__ __forceinline__ unsigned rev8(unsigned v) {
    // reverse the low 8 bits
    return __builtin_bitreverse32(v) >> 24;
}

__device__ __forceinline__ unsigned nib4(const float4 v) {
    return (unsigned)(v.x != 0.0f)
         | ((unsigned)(v.y != 0.0f) << 1)
         | ((unsigned)(v.z != 0.0f) << 2)
         | ((unsigned)(v.w != 0.0f) << 3);
}

// OR across the 4 lanes of a quad using DPP quad_perm (VALU pipe only).
__device__ __forceinline__ unsigned quad_or(unsigned w) {
    // quad_perm [1,0,3,2] = 0xB1  (lane ^ 1)
    w |= (unsigned)__builtin_amdgcn_update_dpp(0, (int)w, 0xB1, 0xF, 0xF, true);
    // quad_perm [2,3,0,1] = 0x4E  (lane ^ 2)
    w |= (unsigned)__builtin_amdgcn_update_dpp(0, (int)w, 0x4E, 0xF, 0xF, true);
    return w;
}

__global__ __launch_bounds__(256) void spike_scale_kernel(
        const float4* __restrict__ x4,
        const float4* __restrict__ k4,
        float4* __restrict__ o4,
        int nvec) {
    int idx = blockIdx.x * 256 + threadIdx.x;
    if (idx >= nvec) return;

    float4 vx = x4[idx];
    float4 vk = k4[idx];

    unsigned g  = (unsigned)(idx & 7);   // this thread's 4 elems within the row
    unsigned sh = g * 4u;

    unsigned nibx = nib4(vx);
    unsigned nibk = nib4(vk);

    // ---- k == 0 test (ignoring k's sign bit): one ballot, no chain ----
    unsigned kmask = (g == 0u) ? 0xEu : 0xFu;       // drop sign bit in lane 0
    unsigned long long ball = __ballot((nibk & kmask) != 0u);
    unsigned lane = (unsigned)(threadIdx.x & 63u);
    bool kz = (((unsigned)(ball >> (lane & 56u)) & 0xFFu) == 0u);

    // ---- gather row bits 0..15 of x and k across the low quad ----
    // lanes g>=4 compute garbage here, but they never use it (me == 0 below)
    unsigned w = quad_or((nibx << ((g & 3u) * 4u))
                       | (nibk << (16u + (g & 3u) * 4u)));
    unsigned xlo = w & 0xFFFFu;     // x bits 0..15 (sign + exponent + m0..m6)
    unsigned klo = w >> 16;         // k bits 0..15

    // ---- identical arithmetic to the harness-verified v1 ----
    unsigned ek   = rev8((klo >> 1) & 0xFFu);                                  // exponent of k
    unsigned val  = 0x80u | (__builtin_bitreverse32((klo >> 9) & 0x7Fu) >> 25);// 1.m (8-bit)
    unsigned s    = (ek - 127u) & 7u;
    unsigned kabs = val >> (7u - s);
    unsigned kfin = (klo & 1u) ? ((0u - kabs) & 0xFFu) : kabs;
    unsigned ex   = rev8((xlo >> 1) & 0xFFu);
    unsigned er   = rev8((ex + kfin) & 0xFFu) << 1;   // new exponent, bits 1..8

    // per-lane recombine: which of my 4 bits are exponent bits?
    unsigned me       = (0x1FEu >> sh) & 0xFu;        // 0xE, 0xF, 0x1, 0, 0, ...
    unsigned scaled_n = ((er >> sh) & me) | (nibx & (me ^ 0xFu));
    unsigned res      = kz ? nibx : scaled_n;

    float4 out;
    out.x = (float)(res & 1u);
    out.y = (float)((res >> 1) & 1u);
    out.z = (float)((res >> 2) & 1u);
    out.w = (float)((res >> 3) & 1u);
    o4[idx] = out;
}

extern "C" void kernel_launch(void* const* d_in, const int* in_sizes, int n_in,
                              void* d_out, int out_size, void* d_ws, size_t ws_size,
                              hipStream_t stream) {
    const float4* x4 = (const float4*)d_in[0];
    const float4* k4 = (const float4*)d_in[1];
    float4* o4 = (float4*)d_out;

    int n_elems = in_sizes[0];          // N * 32 floats
    int nvec    = n_elems / 4;          // float4 vectors
    int blocks  = (nvec + 255) / 256;

    spike_scale_kernel<<<blocks, 256, 0, stream>>>(x4, k4, o4, nvec);
}